// Round 7
// baseline (194.132 us; speedup 1.0000x reference)
//
#include <hip/hip_runtime.h>
#include <stdint.h>

#define N_Q    4096
#define D_K    512
#define D_OUT  16384
#define NCLUST 256

// GEMM: 128x256 tile, BK=32, 8 waves (2Mx4N), 64x64 per wave. Persistent WGs:
// each block does 4 mtiles for one ntile (grid 512 = 2 WG/CU, LDS 72 KB).
// Cross-tile pipeline: next tile's k-stage issued BEFORE the epilogue stores,
// loop-top waits vmcnt(16) (= #stores issued after those loads) so stores
// drain under the next K-loop. Epilogue sC = B-slots 0+1 (32 KB, disjoint
// from prefetch slots A0/B2); lgkm-only barriers (never drain vmcnt there).
#define BM 128
#define BN 256
#define BK 32
#define NT (D_K / BK)   // 16 K-tiles

typedef __attribute__((ext_vector_type(4))) float f32x4;
typedef __attribute__((ext_vector_type(8))) short bf16x8;

// round-to-nearest-even f32 -> bf16
__device__ __forceinline__ uint32_t f2bf(float f) {
  uint32_t u = __float_as_uint(f);
  u += 0x7FFFu + ((u >> 16) & 1u);
  return u >> 16;
}

#define GLOAD_LDS16(g, l)                                         \
  __builtin_amdgcn_global_load_lds(                               \
      (const __attribute__((address_space(1))) void*)(g),         \
      (__attribute__((address_space(3))) void*)(l), 16, 0, 0)

// counted-vmcnt wait fused with barrier (K-loop top); memory clobber pins mem ops
#define WAIT_BAR(N) asm volatile("s_waitcnt vmcnt(" #N ")\n\ts_barrier" ::: "memory")
// lgkm-only barrier (epilogue): does NOT drain vmcnt -> stores stay in flight
#define LBAR() asm volatile("s_waitcnt lgkmcnt(0)\n\ts_barrier" ::: "memory")
// compiler fence: pin issue order of surrounding memory ops (vmcnt bookkeeping)
#define CFENCE() asm volatile("" ::: "memory")

// merged: W f32->bf16 convert (blocks 0..4095) + centroid transpose (4096..4223)
__global__ __launch_bounds__(256) void prep_kernel(const float* __restrict__ weight,
                                                   ushort* __restrict__ W_bf,
                                                   const float* __restrict__ cent,
                                                   float4* __restrict__ centT4,
                                                   float* __restrict__ cmask) {
  int b = blockIdx.x;
  if (b < (D_OUT * D_K / 8) / 256) {
    int i = b * 256 + threadIdx.x;
    const float4* s = reinterpret_cast<const float4*>(weight) + (size_t)i * 2;
    float4 v0 = s[0], v1 = s[1];
    uint4 o;
    o.x = f2bf(v0.x) | (f2bf(v0.y) << 16);
    o.y = f2bf(v0.z) | (f2bf(v0.w) << 16);
    o.z = f2bf(v1.x) | (f2bf(v1.y) << 16);
    o.w = f2bf(v1.z) | (f2bf(v1.w) << 16);
    reinterpret_cast<uint4*>(W_bf)[i] = o;
  } else {
    int bb = b - (D_OUT * D_K / 8) / 256;
    if (bb == 0) cmask[threadIdx.x] = 0.0f;
    int idx = bb * 256 + threadIdx.x;
    int k4 = idx & 127, c = idx >> 7;
    float4 v = *reinterpret_cast<const float4*>(&cent[(size_t)c * D_K + k4 * 4]);
    centT4[(size_t)k4 * NCLUST + c] = v;
  }
}

// 8 queries/block; thread t owns centroid t; fused A f32->bf16 convert.
// f32 routing math throughout (threshold booleans must not flip).
__global__ __launch_bounds__(256) void routing_kernel(const float* __restrict__ input,
                                                      const float4* __restrict__ centT4,
                                                      float* __restrict__ qmask,
                                                      float* __restrict__ cmask,
                                                      ushort* __restrict__ A_bf) {
  __shared__ float lgs[8][NCLUST];
  int c = threadIdx.x;
  int q0 = blockIdx.x * 8;
  const float* __restrict__ inp = input + (size_t)q0 * D_K;

  {
    const float4* s4 = reinterpret_cast<const float4*>(inp) + c * 4;
    float4 x0 = s4[0], x1 = s4[1], x2 = s4[2], x3 = s4[3];
    uint4 o0, o1;
    o0.x = f2bf(x0.x) | (f2bf(x0.y) << 16);
    o0.y = f2bf(x0.z) | (f2bf(x0.w) << 16);
    o0.z = f2bf(x1.x) | (f2bf(x1.y) << 16);
    o0.w = f2bf(x1.z) | (f2bf(x1.w) << 16);
    o1.x = f2bf(x2.x) | (f2bf(x2.y) << 16);
    o1.y = f2bf(x2.z) | (f2bf(x2.w) << 16);
    o1.z = f2bf(x3.x) | (f2bf(x3.y) << 16);
    o1.w = f2bf(x3.z) | (f2bf(x3.w) << 16);
    uint4* dst = reinterpret_cast<uint4*>(A_bf + (size_t)q0 * D_K);
    dst[c * 2] = o0;
    dst[c * 2 + 1] = o1;
  }

  float acc[8] = {0, 0, 0, 0, 0, 0, 0, 0};
  for (int k4 = 0; k4 < D_K / 4; ++k4) {
    float4 v = centT4[(size_t)k4 * NCLUST + c];
#pragma unroll
    for (int q = 0; q < 8; ++q) {
      float4 r = *reinterpret_cast<const float4*>(&inp[q * D_K + k4 * 4]);  // uniform addr
      acc[q] += v.x * r.x + v.y * r.y + v.z * r.z + v.w * r.w;
    }
  }
#pragma unroll
  for (int q = 0; q < 8; ++q) lgs[q][c] = acc[q] * 10.0f;  // /TEMPERATURE
  __syncthreads();

  int wave = c >> 6, lane = c & 63;
#pragma unroll
  for (int qq = 0; qq < 2; ++qq) {
    int q = wave * 2 + qq;
    float4 lv = *reinterpret_cast<const float4*>(&lgs[q][lane * 4]);
    float m = fmaxf(fmaxf(lv.x, lv.y), fmaxf(lv.z, lv.w));
#pragma unroll
    for (int off = 32; off > 0; off >>= 1) m = fmaxf(m, __shfl_xor(m, off));
    float e0 = expf(lv.x - m), e1 = expf(lv.y - m), e2 = expf(lv.z - m), e3 = expf(lv.w - m);
    float s = e0 + e1 + e2 + e3;
#pragma unroll
    for (int off = 32; off > 0; off >>= 1) s += __shfl_xor(s, off);
    float thr = 0.01f * s;
    bool a0 = e0 > thr, a1 = e1 > thr, a2 = e2 > thr, a3 = e3 > thr;
    if (a0) cmask[lane * 4 + 0] = 1.0f;  // benign races: all writers store 1.0
    if (a1) cmask[lane * 4 + 1] = 1.0f;
    if (a2) cmask[lane * 4 + 2] = 1.0f;
    if (a3) cmask[lane * 4 + 3] = 1.0f;
    unsigned long long any = __ballot(a0 | a1 | a2 | a3);
    if (lane == 0) qmask[q0 + q] = any ? 1.0f : 0.0f;
  }
}

__global__ __launch_bounds__(512, 4) void gemm_masked_kernel(
    const ushort* __restrict__ A, const ushort* __restrict__ W,
    const float* __restrict__ bias, const int* __restrict__ assign,
    const float* __restrict__ qmask, const float* __restrict__ cmask,
    float* __restrict__ C) {
  // LDS layout (bytes): [0,16K)=B0 [16K,32K)=B1 [32K,40K)=A0 [40K,48K)=A1
  //                     [48K,56K)=A2 [56K,72K)=B2 ; epilogue sC = [0,32K)
  // tile j uses A-slot j%3, B-slot (j+2)%3  -> tile 0's B lands in B2 (disjoint
  // from sC), so next-mtile tile-0 can be staged before the epilogue stores.
  __shared__ __align__(16) char smem[73728];

  int tid = threadIdx.x;
  int wave = tid >> 6, lane = tid & 63;

  // 512 blocks: xcd = bid&7 owns ntiles [8x,8x+8) (2 MB W-panel L2-resident);
  // mgrp = bid>>6 gives 4 consecutive mtiles per block. 512 = 8*8*8 bijective.
  int bid = blockIdx.x;
  int ntile = (bid & 7) * 8 + ((bid >> 3) & 7);  // 0..63
  int mgrp = bid >> 6;                           // 0..7
  int n0 = ntile * BN;

  int wr = wave >> 2, wc = wave & 3;  // 2x4 wave grid; per-wave C: 64x64

  // staging sources: LDS slot (row,kg) <- global (row, kg ^ ((row>>1)&3))
  int srow = tid >> 2, kgl = tid & 3;
  int ks = (kgl ^ ((srow >> 1) & 3)) * 8;
  const ushort* srcB0 = W + (size_t)(n0 + srow) * D_K + ks;
  const ushort* srcB1 = W + (size_t)(n0 + 128 + srow) * D_K + ks;
  int ldsb = wave * 1024;  // byte offset of this wave's 1KB chunk in a half-region

  const int BOFF[3] = {0, 16384, 57344};

#define STAGE_T(j, srcA) do {                                  \
    char* ab_ = smem + 32768 + ((j) % 3) * 8192 + ldsb;        \
    char* bb_ = smem + BOFF[((j) + 2) % 3] + ldsb;             \
    GLOAD_LDS16((srcA) + (j) * BK, ab_);                       \
    GLOAD_LDS16(srcB0 + (j) * BK, bb_);                        \
    GLOAD_LDS16(srcB1 + (j) * BK, bb_ + 8192);                 \
  } while (0)

  // fragment read indices (swizzled), ushort units within a slot
  int kg0 = lane >> 4, l15 = lane & 15, lr = lane >> 4;
  int aIdx[4], bIdx[4];
#pragma unroll
  for (int m = 0; m < 4; ++m) {
    int r = wr * 64 + m * 16 + l15;
    aIdx[m] = r * 32 + ((kg0 ^ ((r >> 1) & 3)) << 3);
  }
#pragma unroll
  for (int n = 0; n < 4; ++n) {
    int r = wc * 64 + n * 16 + l15;
    bIdx[n] = r * 32 + ((kg0 ^ ((r >> 1) & 3)) << 3);
  }

  // hoisted per-column epilogue terms (ntile fixed for all 4 mtiles)
  float bj[4], rm[4];
#pragma unroll
  for (int n = 0; n < 4; ++n) {
    int col = n0 + wc * 64 + n * 16 + l15;
    bj[n] = bias[col];
    rm[n] = cmask[assign[col]];
  }

  const ushort* srcA = A + (size_t)(mgrp * 4 * BM + srow) * D_K + ks;
  const size_t srcA_step = (size_t)BM * D_K;

  STAGE_T(0, srcA);  // prologue: tile 0 of mtile 0

  for (int mt = 0; mt < 4; ++mt) {
    int m0 = (mgrp * 4 + mt) * BM;
    f32x4 acc[4][4] = {};

#pragma unroll
    for (int t = 0; t < NT; ++t) {
      // loop-top wait: guarantee tile t's 3 loads landed. For mt>0 t==0, the
      // 16 epilogue stores were issued AFTER tile-0's loads -> vmcnt(16)
      // retires the loads while stores stay in flight.
      if (t == 0) {
        if (mt) { WAIT_BAR(16); } else { WAIT_BAR(0); }
      } else if (t < NT - 1) { WAIT_BAR(3); }
      else { WAIT_BAR(0); }

      const ushort* sa = (const ushort*)(smem + 32768 + (t % 3) * 8192);
      const ushort* sb = (const ushort*)(smem + BOFF[(t + 2) % 3]);
      bf16x8 af[4], bf[4];
#pragma unroll
      for (int n = 0; n < 4; ++n) bf[n] = *reinterpret_cast<const bf16x8*>(&sb[bIdx[n]]);
#pragma unroll
      for (int m = 0; m < 4; ++m) af[m] = *reinterpret_cast<const bf16x8*>(&sa[aIdx[m]]);

      if (t == 0) { STAGE_T(1, srcA); STAGE_T(2, srcA); }
      else if (t + 2 < NT) { STAGE_T(t + 2, srcA); }

      __builtin_amdgcn_s_setprio(1);
#pragma unroll
      for (int m = 0; m < 4; ++m)
#pragma unroll
        for (int n = 0; n < 4; ++n)
          acc[m][n] = __builtin_amdgcn_mfma_f32_16x16x32_bf16(af[m], bf[n], acc[m][n], 0, 0, 0);
      __builtin_amdgcn_s_setprio(0);
    }

    LBAR();  // all waves' tile reads drained; sC region (B0+B1) reusable

    // epilogue: per m-chunk, sC[32][256] transpose -> regs -> full-line nt stores.
    // tile-0 of next mtile staged after chunk 0's read, BEFORE any stores.
    float* sC = reinterpret_cast<float*>(smem);
    const ushort* srcAn = srcA + ((mt < 3) ? srcA_step : 0);
#pragma unroll
    for (int m = 0; m < 4; ++m) {
      float4 qm = *reinterpret_cast<const float4*>(&qmask[m0 + wr * 64 + m * 16 + lr * 4]);
      int rl = wr * 16 + lr * 4;
#pragma unroll
      for (int n = 0; n < 4; ++n) {
        int cc = wc * 64 + n * 16 + l15;
        sC[(rl + 0) * 256 + cc] = (acc[m][n][0] + bj[n]) * qm.x * rm[n];
        sC[(rl + 1) * 256 + cc] = (acc[m][n][1] + bj[n]) * qm.y * rm[n];
        sC[(rl + 2) * 256 + cc] = (acc[m][n][2] + bj[n]) * qm.z * rm[n];
        sC[(rl + 3) * 256 + cc] = (acc[m][n][3] + bj[n]) * qm.w * rm[n];
      }
      LBAR();
      f32x4 v[4];
#pragma unroll
      for (int i = 0; i < 4; ++i)
        v[i] = *reinterpret_cast<const f32x4*>(&sC[(wave * 4 + i) * 256 + lane * 4]);
      LBAR();
      if (m == 0 && mt < 3) { STAGE_T(0, srcAn); CFENCE(); }  // loads BEFORE stores
#pragma unroll
      for (int i = 0; i < 4; ++i) {
        int rr = wave * 4 + i;
        int grow = m0 + (rr >> 4) * 64 + m * 16 + (rr & 15);
        __builtin_nontemporal_store(
            v[i], reinterpret_cast<f32x4*>(&C[(size_t)grow * D_OUT + n0 + lane * 4]));
      }
      CFENCE();
    }
    srcA = srcAn;
  }
#undef STAGE_T
}

extern "C" void kernel_launch(void* const* d_in, const int* in_sizes, int n_in,
                              void* d_out, int out_size, void* d_ws, size_t ws_size,
                              hipStream_t stream) {
  const float* input     = (const float*)d_in[0];
  const float* weight    = (const float*)d_in[1];
  const float* bias      = (const float*)d_in[2];
  const float* centroids = (const float*)d_in[3];
  const int*   assign    = (const int*)d_in[4];
  float* out = (float*)d_out;

  // ws layout (bytes):
  //   A_bf16 : 0          (4 MiB)
  //   W_bf16 : 4,194,304  (16 MiB)
  //   qmask  : 20,971,520 (16 KB)
  //   cmask  : 20,987,904 (1 KB)
  //   centT4 : 21,000,192 (512 KB)
  char* ws = (char*)d_ws;
  ushort* A_bf   = (ushort*)ws;
  ushort* W_bf   = (ushort*)(ws + 4194304);
  float*  qmask  = (float*)(ws + 20971520);
  float*  cmask  = (float*)(ws + 20987904);
  float4* centT4 = (float4*)(ws + 21000192);

  prep_kernel<<<4224, 256, 0, stream>>>(weight, W_bf, centroids, centT4, cmask);
  routing_kernel<<<N_Q / 8, 256, 0, stream>>>(input, centT4, qmask, cmask, A_bf);
  gemm_masked_kernel<<<512, 512, 0, stream>>>(A_bf, W_bf, bias, assign, qmask, cmask, out);
}

// Round 8
// 133.148 us; speedup vs baseline: 1.4580x; 1.4580x over previous
//
#include <hip/hip_runtime.h>
#include <stdint.h>

#define N_Q    4096
#define D_K    512
#define D_OUT  16384
#define NCLUST 256

// GEMM: 128x128 tile, BK=32, 4 waves (2x2), 64x64 per wave. Ring-3 LDS
// (48 KB) -> 3 WGs/CU co-resident (round-8 lever: inter-WG overlap of
// K-loop / epilogue store-drain across 3 independent WGs; barrier groups
// half as wide). Counted vmcnt, T2 swizzle, setprio, XCD panel mapping,
// LDS-transposed epilogue (SCP=132, non-pow2) with full-line nt stores.
#define BM 128
#define BN 128
#define BK 32
#define NT (D_K / BK)   // 16 K-tiles
#define SCP 132         // sC row stride in floats (non-pow2: 2-way/free banks)

typedef __attribute__((ext_vector_type(4))) float f32x4;
typedef __attribute__((ext_vector_type(8))) short bf16x8;

// round-to-nearest-even f32 -> bf16
__device__ __forceinline__ uint32_t f2bf(float f) {
  uint32_t u = __float_as_uint(f);
  u += 0x7FFFu + ((u >> 16) & 1u);
  return u >> 16;
}

#define GLOAD_LDS16(g, l)                                         \
  __builtin_amdgcn_global_load_lds(                               \
      (const __attribute__((address_space(1))) void*)(g),         \
      (__attribute__((address_space(3))) void*)(l), 16, 0, 0)

// counted-vmcnt wait fused with barrier (K-loop top)
#define WAIT_BAR(N) asm volatile("s_waitcnt vmcnt(" #N ")\n\ts_barrier" ::: "memory")
// lgkm-only barrier (epilogue): never drains vmcnt -> nt stores stay in flight
#define LBAR() asm volatile("s_waitcnt lgkmcnt(0)\n\ts_barrier" ::: "memory")

// merged: W f32->bf16 convert (blocks 0..4095) + centroid transpose (4096..4223)
__global__ __launch_bounds__(256) void prep_kernel(const float* __restrict__ weight,
                                                   ushort* __restrict__ W_bf,
                                                   const float* __restrict__ cent,
                                                   float4* __restrict__ centT4,
                                                   float* __restrict__ cmask) {
  int b = blockIdx.x;
  if (b < (D_OUT * D_K / 8) / 256) {
    int i = b * 256 + threadIdx.x;
    const float4* s = reinterpret_cast<const float4*>(weight) + (size_t)i * 2;
    float4 v0 = s[0], v1 = s[1];
    uint4 o;
    o.x = f2bf(v0.x) | (f2bf(v0.y) << 16);
    o.y = f2bf(v0.z) | (f2bf(v0.w) << 16);
    o.z = f2bf(v1.x) | (f2bf(v1.y) << 16);
    o.w = f2bf(v1.z) | (f2bf(v1.w) << 16);
    reinterpret_cast<uint4*>(W_bf)[i] = o;
  } else {
    int bb = b - (D_OUT * D_K / 8) / 256;
    if (bb == 0) cmask[threadIdx.x] = 0.0f;
    int idx = bb * 256 + threadIdx.x;
    int k4 = idx & 127, c = idx >> 7;
    float4 v = *reinterpret_cast<const float4*>(&cent[(size_t)c * D_K + k4 * 4]);
    centT4[(size_t)k4 * NCLUST + c] = v;
  }
}

// 8 queries/block; thread t owns centroid t; fused A f32->bf16 convert.
// f32 routing math throughout (threshold booleans must not flip).
__global__ __launch_bounds__(256) void routing_kernel(const float* __restrict__ input,
                                                      const float4* __restrict__ centT4,
                                                      float* __restrict__ qmask,
                                                      float* __restrict__ cmask,
                                                      ushort* __restrict__ A_bf) {
  __shared__ float lgs[8][NCLUST];
  int c = threadIdx.x;
  int q0 = blockIdx.x * 8;
  const float* __restrict__ inp = input + (size_t)q0 * D_K;

  {
    const float4* s4 = reinterpret_cast<const float4*>(inp) + c * 4;
    float4 x0 = s4[0], x1 = s4[1], x2 = s4[2], x3 = s4[3];
    uint4 o0, o1;
    o0.x = f2bf(x0.x) | (f2bf(x0.y) << 16);
    o0.y = f2bf(x0.z) | (f2bf(x0.w) << 16);
    o0.z = f2bf(x1.x) | (f2bf(x1.y) << 16);
    o0.w = f2bf(x1.z) | (f2bf(x1.w) << 16);
    o1.x = f2bf(x2.x) | (f2bf(x2.y) << 16);
    o1.y = f2bf(x2.z) | (f2bf(x2.w) << 16);
    o1.z = f2bf(x3.x) | (f2bf(x3.y) << 16);
    o1.w = f2bf(x3.z) | (f2bf(x3.w) << 16);
    uint4* dst = reinterpret_cast<uint4*>(A_bf + (size_t)q0 * D_K);
    dst[c * 2] = o0;
    dst[c * 2 + 1] = o1;
  }

  float acc[8] = {0, 0, 0, 0, 0, 0, 0, 0};
  for (int k4 = 0; k4 < D_K / 4; ++k4) {
    float4 v = centT4[(size_t)k4 * NCLUST + c];
#pragma unroll
    for (int q = 0; q < 8; ++q) {
      float4 r = *reinterpret_cast<const float4*>(&inp[q * D_K + k4 * 4]);  // uniform addr
      acc[q] += v.x * r.x + v.y * r.y + v.z * r.z + v.w * r.w;
    }
  }
#pragma unroll
  for (int q = 0; q < 8; ++q) lgs[q][c] = acc[q] * 10.0f;  // /TEMPERATURE
  __syncthreads();

  int wave = c >> 6, lane = c & 63;
#pragma unroll
  for (int qq = 0; qq < 2; ++qq) {
    int q = wave * 2 + qq;
    float4 lv = *reinterpret_cast<const float4*>(&lgs[q][lane * 4]);
    float m = fmaxf(fmaxf(lv.x, lv.y), fmaxf(lv.z, lv.w));
#pragma unroll
    for (int off = 32; off > 0; off >>= 1) m = fmaxf(m, __shfl_xor(m, off));
    float e0 = expf(lv.x - m), e1 = expf(lv.y - m), e2 = expf(lv.z - m), e3 = expf(lv.w - m);
    float s = e0 + e1 + e2 + e3;
#pragma unroll
    for (int off = 32; off > 0; off >>= 1) s += __shfl_xor(s, off);
    float thr = 0.01f * s;
    bool a0 = e0 > thr, a1 = e1 > thr, a2 = e2 > thr, a3 = e3 > thr;
    if (a0) cmask[lane * 4 + 0] = 1.0f;  // benign races: all writers store 1.0
    if (a1) cmask[lane * 4 + 1] = 1.0f;
    if (a2) cmask[lane * 4 + 2] = 1.0f;
    if (a3) cmask[lane * 4 + 3] = 1.0f;
    unsigned long long any = __ballot(a0 | a1 | a2 | a3);
    if (lane == 0) qmask[q0 + q] = any ? 1.0f : 0.0f;
  }
}

__global__ __launch_bounds__(256, 3) void gemm_masked_kernel(
    const ushort* __restrict__ A, const ushort* __restrict__ W,
    const float* __restrict__ bias, const int* __restrict__ assign,
    const float* __restrict__ qmask, const float* __restrict__ cmask,
    float* __restrict__ C) {
  // LDS 48 KB: slot j at j*16K = {A tile 8K | B tile 8K}. Epilogue reuses
  // the front 17 KB as sC[32][SCP] after the K-loop (block-terminal).
  __shared__ __align__(16) char smem[49152];

  int tid = threadIdx.x;
  int wave = tid >> 6, lane = tid & 63;

  // XCD mapping: xcd = bid&7 owns ntiles [16x,16x+16); ntile is the FAST index
  // within an XCD so the whole 2 MB W-set (16 panels x 128 KB) cycles while
  // L2-resident; A-panel (128 KB) shared by the 16 co-running ntile-blocks.
  // 4096 % 8 == 0 -> bijective.
  int bid = blockIdx.x;
  int idx = bid >> 3;                         // 0..511
  int ntile = (bid & 7) * 16 + (idx & 15);    // 0..127
  int mtile = idx >> 4;                       // 0..31
  int m0 = mtile * BM, n0 = ntile * BN;

  int wr = wave >> 1, wc = wave & 1;  // 2x2 wave grid; per-wave C: 64x64

  // staging: LDS (row,kg) <- global (row, kg ^ ((row>>1)&3)); linear LDS dest,
  // pre-swizzled per-lane source (rule #21). ((64+r)>>1)&3 == ((r>>1)&3) ✓.
  int srow = tid >> 2, kg = tid & 3;
  int ks = (kg ^ ((srow >> 1) & 3)) * 8;
  const ushort* srcA0 = A + (size_t)(m0 + srow) * D_K + ks;       // rows 0..63
  const ushort* srcA1 = srcA0 + (size_t)64 * D_K;                 // rows 64..127
  const ushort* srcB0 = W + (size_t)(n0 + srow) * D_K + ks;
  const ushort* srcB1 = srcB0 + (size_t)64 * D_K;
  int wo = wave << 10;  // wave's 1 KB chunk within each 4 KB op region

#define STAGE(j) do {                                    \
    char* sl_ = smem + ((j) % 3) * 16384 + wo;           \
    GLOAD_LDS16(srcA0 + (j) * BK, sl_);                  \
    GLOAD_LDS16(srcA1 + (j) * BK, sl_ + 4096);           \
    GLOAD_LDS16(srcB0 + (j) * BK, sl_ + 8192);           \
    GLOAD_LDS16(srcB1 + (j) * BK, sl_ + 12288);          \
  } while (0)

  // fragment read indices (swizzled), ushort units within a slot
  int kg0 = lane >> 4, l15 = lane & 15, lr = lane >> 4;
  int aIdx[4], bIdx[4];
#pragma unroll
  for (int m = 0; m < 4; ++m) {
    int r = wr * 64 + m * 16 + l15;
    aIdx[m] = r * 32 + ((kg0 ^ ((r >> 1) & 3)) << 3);
  }
#pragma unroll
  for (int n = 0; n < 4; ++n) {
    int r = wc * 64 + n * 16 + l15;
    bIdx[n] = 4096 + r * 32 + ((kg0 ^ ((r >> 1) & 3)) << 3);  // B at +8 KB
  }

  f32x4 acc[4][4] = {};

  STAGE(0);
  STAGE(1);

#pragma unroll
  for (int t = 0; t < NT; ++t) {
    // loop top: tile t's 4 loads are oldest; tile t+1's 4 stay in flight.
    if (t < NT - 1) { WAIT_BAR(4); } else { WAIT_BAR(0); }

    const ushort* sl = (const ushort*)(smem + (t % 3) * 16384);
    bf16x8 af[4], bf[4];
#pragma unroll
    for (int n = 0; n < 4; ++n) bf[n] = *reinterpret_cast<const bf16x8*>(&sl[bIdx[n]]);
#pragma unroll
    for (int m = 0; m < 4; ++m) af[m] = *reinterpret_cast<const bf16x8*>(&sl[aIdx[m]]);
    if (t + 2 < NT) STAGE(t + 2);  // slot (t+2)%3 == (t-1)%3: reads retired pre-barrier

    __builtin_amdgcn_s_setprio(1);
#pragma unroll
    for (int m = 0; m < 4; ++m)
#pragma unroll
      for (int n = 0; n < 4; ++n)
        acc[m][n] = __builtin_amdgcn_mfma_f32_16x16x32_bf16(af[m], bf[n], acc[m][n], 0, 0, 0);
    __builtin_amdgcn_s_setprio(0);
    // closing barrier is next iteration's WAIT_BAR (or loop exit)
  }
#undef STAGE

  LBAR();  // all tile LDS reads retired; smem reusable as sC

  // LDS-transposed epilogue: per m-chunk, masked acc -> sC[32][SCP] ->
  // full-line nt stores (32 lanes x 16B = 512 B contiguous per row).
  float* sC = reinterpret_cast<float*>(smem);
  float bj[4], rm[4];
#pragma unroll
  for (int n = 0; n < 4; ++n) {
    int col = n0 + wc * 64 + n * 16 + l15;
    bj[n] = bias[col];
    rm[n] = cmask[assign[col]];
  }
#pragma unroll
  for (int m = 0; m < 4; ++m) {
    float4 qm = *reinterpret_cast<const float4*>(&qmask[m0 + wr * 64 + m * 16 + lr * 4]);
    int rl = wr * 16 + lr * 4;  // sC local row
#pragma unroll
    for (int n = 0; n < 4; ++n) {
      int cc = wc * 64 + n * 16 + l15;
      sC[(rl + 0) * SCP + cc] = (acc[m][n][0] + bj[n]) * qm.x * rm[n];
      sC[(rl + 1) * SCP + cc] = (acc[m][n][1] + bj[n]) * qm.y * rm[n];
      sC[(rl + 2) * SCP + cc] = (acc[m][n][2] + bj[n]) * qm.z * rm[n];
      sC[(rl + 3) * SCP + cc] = (acc[m][n][3] + bj[n]) * qm.w * rm[n];
    }
    LBAR();
    f32x4 v[4];
#pragma unroll
    for (int i = 0; i < 4; ++i) {
      int s = wave * 8 + i * 2 + (lane >> 5);
      v[i] = *reinterpret_cast<const f32x4*>(&sC[s * SCP + (lane & 31) * 4]);
    }
    LBAR();
#pragma unroll
    for (int i = 0; i < 4; ++i) {
      int s = wave * 8 + i * 2 + (lane >> 5);
      int grow = m0 + (s >> 4) * 64 + m * 16 + (s & 15);
      __builtin_nontemporal_store(
          v[i], reinterpret_cast<f32x4*>(&C[(size_t)grow * D_OUT + n0 + (lane & 31) * 4]));
    }
  }
}

extern "C" void kernel_launch(void* const* d_in, const int* in_sizes, int n_in,
                              void* d_out, int out_size, void* d_ws, size_t ws_size,
                              hipStream_t stream) {
  const float* input     = (const float*)d_in[0];
  const float* weight    = (const float*)d_in[1];
  const float* bias      = (const float*)d_in[2];
  const float* centroids = (const float*)d_in[3];
  const int*   assign    = (const int*)d_in[4];
  float* out = (float*)d_out;

  // ws layout (bytes):
  //   A_bf16 : 0          (4 MiB)
  //   W_bf16 : 4,194,304  (16 MiB)
  //   qmask  : 20,971,520 (16 KB)
  //   cmask  : 20,987,904 (1 KB)
  //   centT4 : 21,000,192 (512 KB)
  char* ws = (char*)d_ws;
  ushort* A_bf   = (ushort*)ws;
  ushort* W_bf   = (ushort*)(ws + 4194304);
  float*  qmask  = (float*)(ws + 20971520);
  float*  cmask  = (float*)(ws + 20987904);
  float4* centT4 = (float4*)(ws + 21000192);

  prep_kernel<<<4224, 256, 0, stream>>>(weight, W_bf, centroids, centT4, cmask);
  routing_kernel<<<N_Q / 8, 256, 0, stream>>>(input, centT4, qmask, cmask, A_bf);
  gemm_masked_kernel<<<(N_Q / BM) * (D_OUT / BN), 256, 0, stream>>>(
      A_bf, W_bf, bias, assign, qmask, cmask, out);
}